// Round 1
// baseline (1396.599 us; speedup 1.0000x reference)
//
#include <hip/hip_runtime.h>
#include <math.h>

#define NB 2048
#define NC 64
#define NT 512
#define NF 17
#define NCOL (NC * NF)   // 1088
#define NFREQ 129

// Position of channel c in sorted(f'ch{i}_') order.
__device__ __constant__ int POS[64] = {
   0, 11, 22, 33, 44, 55, 60, 61, 62, 63,   // c = 0..9
   1,  2,  3,  4,  5,  6,  7,  8,  9, 10,   // c = 10..19
  12, 13, 14, 15, 16, 17, 18, 19, 20, 21,   // c = 20..29
  23, 24, 25, 26, 27, 28, 29, 30, 31, 32,   // c = 30..39
  34, 35, 36, 37, 38, 39, 40, 41, 42, 43,   // c = 40..49
  45, 46, 47, 48, 49, 50, 51, 52, 53, 54,   // c = 50..59
  56, 57, 58, 59                             // c = 60..63
};

// Feature index map (sorted names):
// 0 alpha_power 1 alpha_relative 2 beta_power 3 beta_relative 4 delta_power
// 5 delta_relative 6 entropy 7 gamma_power 8 gamma_relative 9 kurtosis
// 10 mean 11 peak_freq 12 rms 13 skew 14 std 15 theta_power 16 theta_relative

__global__ void init_tables(float* __restrict__ win, float2* __restrict__ tw) {
    int t = threadIdx.x;  // 256 threads
    double ang = (2.0 * 3.14159265358979323846 / 256.0) * (double)t;
    double cv = cos(ang), sv = sin(ang);
    win[t] = (float)(0.5 - 0.5 * cv);
    tw[t] = make_float2((float)cv, (float)sv);
}

template <bool HAS_TAB>
__global__ __launch_bounds__(256) void feat_kernel(
    const float* __restrict__ x,
    const float* __restrict__ gwin, const float2* __restrict__ gtw,
    float* __restrict__ out) {
    __shared__ float xs[512];
    __shared__ float vseg[256];
    __shared__ float2 Tl[16 * 17];   // padded stride 17 to break bank aliasing
    __shared__ float winS[256];
    __shared__ float2 twS[256];
    __shared__ float red[16];
    __shared__ float psd_s[NFREQ];
    __shared__ float feat[NF];
    __shared__ unsigned int hist[10];

    const int t = threadIdx.x;
    const int bc = blockIdx.x;
    const int b = bc >> 6;
    const int c = bc & 63;
    const int wid = t >> 6, lane = t & 63;
    const float* xp = x + (size_t)bc * NT;

    float2 xv = reinterpret_cast<const float2*>(xp)[t];
    xs[2 * t] = xv.x;
    xs[2 * t + 1] = xv.y;
    if (HAS_TAB) {
        winS[t] = gwin[t];
        twS[t] = gtw[t];
    } else {
        float ang = (float)t * (6.28318530717958647692f / 256.0f);
        float sv, cv;
        sincosf(ang, &sv, &cv);
        winS[t] = 0.5f - 0.5f * cv;
        twS[t] = make_float2(cv, sv);
    }
    if (t < 10) hist[t] = 0u;
    __syncthreads();

    // ---- pass 1: sum, sum x^2, min, max ----
    float s1 = xv.x + xv.y;
    float s2 = xv.x * xv.x + xv.y * xv.y;
    float mn = fminf(xv.x, xv.y);
    float mx = fmaxf(xv.x, xv.y);
#pragma unroll
    for (int off = 32; off; off >>= 1) {
        s1 += __shfl_down(s1, off, 64);
        s2 += __shfl_down(s2, off, 64);
        mn = fminf(mn, __shfl_down(mn, off, 64));
        mx = fmaxf(mx, __shfl_down(mx, off, 64));
    }
    if (lane == 0) {
        red[wid * 4 + 0] = s1; red[wid * 4 + 1] = s2;
        red[wid * 4 + 2] = mn; red[wid * 4 + 3] = mx;
    }
    __syncthreads();
    const float S1 = red[0] + red[4] + red[8] + red[12];
    const float S2 = red[1] + red[5] + red[9] + red[13];
    const float MN = fminf(fminf(red[2], red[6]), fminf(red[10], red[14]));
    const float MX = fmaxf(fmaxf(red[3], red[7]), fmaxf(red[11], red[15]));
    __syncthreads();
    const float mean = S1 * (1.0f / 512.0f);

    // ---- pass 2: centered moments ----
    float a = xv.x - mean, d = xv.y - mean;
    float a2 = a * a, d2 = d * d;
    float c2 = a2 + d2;
    float c3 = a2 * a + d2 * d;
    float c4 = a2 * a2 + d2 * d2;
#pragma unroll
    for (int off = 32; off; off >>= 1) {
        c2 += __shfl_down(c2, off, 64);
        c3 += __shfl_down(c3, off, 64);
        c4 += __shfl_down(c4, off, 64);
    }
    if (lane == 0) {
        red[wid * 4 + 0] = c2; red[wid * 4 + 1] = c3; red[wid * 4 + 2] = c4;
    }
    __syncthreads();
    const float m2 = (red[0] + red[4] + red[8] + red[12]) * (1.0f / 512.0f);
    const float m3 = (red[1] + red[5] + red[9] + red[13]) * (1.0f / 512.0f);
    const float m4 = (red[2] + red[6] + red[10] + red[14]) * (1.0f / 512.0f);
    __syncthreads();

    // ---- histogram (bit-exact fp32: sub, IEEE div, mul, trunc) ----
    {
        float w = MX - MN;
        float safew = (w > 0.0f) ? w : 1.0f;
        int b0 = (int)((xv.x - MN) / safew * 10.0f);
        int b1 = (int)((xv.y - MN) / safew * 10.0f);
        b0 = b0 < 0 ? 0 : (b0 > 9 ? 9 : b0);
        b1 = b1 < 0 ? 0 : (b1 > 9 ? 9 : b1);
        atomicAdd(&hist[b0], 1u);
        atomicAdd(&hist[b1], 1u);
    }
    __syncthreads();

    if (t == 0) {
        float e = 0.0f;
#pragma unroll
        for (int i = 0; i < 10; i++) {
            float p = (float)hist[i] * (1.0f / 512.0f);
            if (p > 0.0f) e += p * logf(p);
        }
        feat[6] = -e;
        feat[10] = mean;
        float stdv = sqrtf(m2);
        feat[14] = stdv;
        feat[13] = m3 / (m2 * stdv);          // m3 / m2^1.5
        feat[9] = m4 / (m2 * m2) - 3.0f;
        feat[12] = sqrtf(S2 * (1.0f / 512.0f));
    }

    // ---- Welch PSD: 3 segments, radix 16x16 DFT ----
    float psdacc = 0.0f;
    for (int s = 0; s < 3; s++) {
        float val = xs[s * 128 + t];
        float sv = val;
#pragma unroll
        for (int off = 32; off; off >>= 1) sv += __shfl_down(sv, off, 64);
        __syncthreads();                 // protect red reuse
        if (lane == 0) red[wid] = sv;
        __syncthreads();
        float smean = (red[0] + red[1] + red[2] + red[3]) * (1.0f / 256.0f);
        vseg[t] = winS[t] * (val - smean);   // detrend then window
        __syncthreads();

        // stage 1: T[r][n0] = sum_n1 v[16*n1+n0] * W^(16*r*n1)
        {
            int r = t >> 4, n0 = t & 15;
            float tr = 0.0f, ti = 0.0f;
            int rstep = (r * 16) & 255;
#pragma unroll
            for (int n1 = 0; n1 < 16; n1++) {
                float v = vseg[(n1 << 4) + n0];
                int m = (rstep * n1) & 255;
                float2 w2 = twS[m];       // W^m = (cos, -i sin)
                tr = fmaf(v, w2.x, tr);
                ti = fmaf(v, -w2.y, ti);
            }
            Tl[r * 17 + n0] = make_float2(tr, ti);
        }
        __syncthreads();

        // stage 2: X_k = sum_n0 W^(k*n0) * T[k&15][n0]
        if (t < NFREQ) {
            int rr = t & 15;
            float xr = 0.0f, xi = 0.0f;
#pragma unroll
            for (int n0 = 0; n0 < 16; n0++) {
                float2 Tv = Tl[rr * 17 + n0];
                int m = (t * n0) & 255;
                float2 w2 = twS[m];
                // (c - i s)(Tr + i Ti) = (c*Tr + s*Ti) + i(c*Ti - s*Tr)
                xr = fmaf(w2.x, Tv.x, fmaf(w2.y, Tv.y, xr));
                xi = fmaf(w2.x, Tv.y, fmaf(-w2.y, Tv.x, xi));
            }
            psdacc = fmaf(xr, xr, fmaf(xi, xi, psdacc));
        }
        __syncthreads();                 // before vseg/Tl overwrite
    }

    if (t < NFREQ) {
        float dbl = (t == 0 || t == 128) ? 1.0f : 2.0f;
        psd_s[t] = psdacc * dbl * ((1.0f / 12288.0f) * (1.0f / 3.0f));
    }
    __syncthreads();

    // ---- bands + argmax on wave 0 ----
    if (t < 64) {
        float tot = 0, al = 0, be = 0, de = 0, ga = 0, th = 0;
        float bv = -1.0f;
        int bi_ = 0;
        auto wt = [](int k, int lo, int hi) -> float {
            if (k < lo || k > hi) return 0.0f;
            return (k == lo || k == hi) ? 0.25f : 0.5f;
        };
        auto process = [&](int k, float p) {
            tot += wt(k, 0, 128) * p;
            al += wt(k, 16, 24) * p;
            be += wt(k, 24, 60) * p;
            de += wt(k, 1, 8) * p;
            ga += wt(k, 60, 90) * p;
            th += wt(k, 8, 16) * p;
            if (p > bv) { bv = p; bi_ = k; }
        };
        process(t, psd_s[t]);
        process(t + 64, psd_s[t + 64]);   // t+64 in [64,127]
        if (t == 0) process(128, psd_s[128]);
#pragma unroll
        for (int m = 32; m; m >>= 1) {
            tot += __shfl_xor(tot, m, 64);
            al += __shfl_xor(al, m, 64);
            be += __shfl_xor(be, m, 64);
            de += __shfl_xor(de, m, 64);
            ga += __shfl_xor(ga, m, 64);
            th += __shfl_xor(th, m, 64);
            float ov = __shfl_xor(bv, m, 64);
            int oi = __shfl_xor(bi_, m, 64);
            if (ov > bv || (ov == bv && oi < bi_)) { bv = ov; bi_ = oi; }
        }
        if (t == 0) {
            feat[0] = al; feat[2] = be; feat[4] = de; feat[7] = ga; feat[15] = th;
            bool ok = tot > 1e-6f;
            feat[1] = ok ? al / tot : 0.0f;
            feat[3] = ok ? be / tot : 0.0f;
            feat[5] = ok ? de / tot : 0.0f;
            feat[8] = ok ? ga / tot : 0.0f;
            feat[16] = ok ? th / tot : 0.0f;
            feat[11] = 0.5f * (float)bi_;
        }
    }
    __syncthreads();

    if (t < NF) out[(size_t)b * NCOL + POS[c] * NF + t] = feat[t];
}

__global__ __launch_bounds__(256) void znorm_kernel(float* __restrict__ fm) {
    __shared__ float red[4];
    const int col = blockIdx.x;    // 1088 columns
    const int t = threadIdx.x;
    const int wid = t >> 6, lane = t & 63;
    float v[8];
    float s = 0.0f;
#pragma unroll
    for (int i = 0; i < 8; i++) {
        v[i] = fm[(size_t)(i * 256 + t) * NCOL + col];
        s += v[i];
    }
#pragma unroll
    for (int off = 32; off; off >>= 1) s += __shfl_down(s, off, 64);
    if (lane == 0) red[wid] = s;
    __syncthreads();
    const float mu = (red[0] + red[1] + red[2] + red[3]) * (1.0f / 2048.0f);
    __syncthreads();
    float q = 0.0f;
#pragma unroll
    for (int i = 0; i < 8; i++) {
        float dd = v[i] - mu;
        q += dd * dd;
    }
#pragma unroll
    for (int off = 32; off; off >>= 1) q += __shfl_down(q, off, 64);
    if (lane == 0) red[wid] = q;
    __syncthreads();
    const float sd = sqrtf((red[0] + red[1] + red[2] + red[3]) * (1.0f / 2048.0f));
    const float den = sd + 1e-6f;
#pragma unroll
    for (int i = 0; i < 8; i++)
        fm[(size_t)(i * 256 + t) * NCOL + col] = (v[i] - mu) / den;
}

extern "C" void kernel_launch(void* const* d_in, const int* in_sizes, int n_in,
                              void* d_out, int out_size, void* d_ws, size_t ws_size,
                              hipStream_t stream) {
    const float* x = (const float*)d_in[0];
    float* out = (float*)d_out;
    if (d_ws != nullptr && ws_size >= 4096) {
        float* win = (float*)d_ws;
        float2* tw = (float2*)((char*)d_ws + 1024);
        init_tables<<<1, 256, 0, stream>>>(win, tw);
        feat_kernel<true><<<NB * NC, 256, 0, stream>>>(x, win, tw, out);
    } else {
        feat_kernel<false><<<NB * NC, 256, 0, stream>>>(x, nullptr, nullptr, out);
    }
    znorm_kernel<<<NCOL, 256, 0, stream>>>(out);
}

// Round 2
// 651.309 us; speedup vs baseline: 2.1443x; 2.1443x over previous
//
#include <hip/hip_runtime.h>
#include <math.h>

#define NB 2048
#define NC 64
#define NF 17
#define NCOL (NC * NF)   // 1088

// Position of channel c in sorted(f'ch{i}_') order.
__device__ __constant__ int POS[64] = {
   0, 11, 22, 33, 44, 55, 60, 61, 62, 63,   // c = 0..9
   1,  2,  3,  4,  5,  6,  7,  8,  9, 10,   // c = 10..19
  12, 13, 14, 15, 16, 17, 18, 19, 20, 21,   // c = 20..29
  23, 24, 25, 26, 27, 28, 29, 30, 31, 32,   // c = 30..39
  34, 35, 36, 37, 38, 39, 40, 41, 42, 43,   // c = 40..49
  45, 46, 47, 48, 49, 50, 51, 52, 53, 54,   // c = 50..59
  56, 57, 58, 59                             // c = 60..63
};

// Feature index map (sorted names):
// 0 alpha_power 1 alpha_relative 2 beta_power 3 beta_relative 4 delta_power
// 5 delta_relative 6 entropy 7 gamma_power 8 gamma_relative 9 kurtosis
// 10 mean 11 peak_freq 12 rms 13 skew 14 std 15 theta_power 16 theta_relative

__global__ void init_tables(float* __restrict__ win, float2* __restrict__ tw) {
    int t = threadIdx.x;  // 256 threads
    double ang = (2.0 * 3.14159265358979323846 / 256.0) * (double)t;
    double cv = cos(ang), sv = sin(ang);
    win[t] = (float)(0.5 - 0.5 * cv);
    tw[t] = make_float2((float)cv, (float)sv);
}

// One wave (64 lanes) processes one (b,c) channel end-to-end.
// Block = 4 waves = 4 channels; the only __syncthreads is the table staging.
template <bool HAS_TAB>
__global__ __launch_bounds__(256) void feat_kernel(
    const float* __restrict__ x,
    const float* __restrict__ gwin, const float2* __restrict__ gtw,
    float* __restrict__ out)
{
    __shared__ __align__(16) float winS[256];
    __shared__ float2 twS[256];      // (cos, sin) of 2*pi*m/256
    __shared__ float2 tw16S[16];     // (cos, sin) of 2*pi*m/16
    // per-wave scratch: vseg[256] floats + T[16][18] float2 (= 576 floats)
    __shared__ __align__(16) float wmem[4 * 832];
    __shared__ unsigned histS[4][10];

    const int t = threadIdx.x;
    const int wid = t >> 6, l = t & 63;
    const int bc = (blockIdx.x << 2) + wid;
    const int b = bc >> 6, c = bc & 63;

    if (HAS_TAB) {
        winS[t] = gwin[t];
        twS[t] = gtw[t];
        if (t < 16) tw16S[t] = gtw[t << 4];
    } else {
        float ang = (float)t * (6.28318530717958647692f / 256.0f);
        float sv, cv;
        sincosf(ang, &sv, &cv);
        winS[t] = 0.5f - 0.5f * cv;
        twS[t] = make_float2(cv, sv);
        if (t < 16) {
            float a2 = (float)t * (6.28318530717958647692f / 16.0f);
            float s2v, c2v; sincosf(a2, &s2v, &c2v);
            tw16S[t] = make_float2(c2v, s2v);
        }
    }
    __syncthreads();

    float* vseg = &wmem[wid * 832];
    float2* T = reinterpret_cast<float2*>(&wmem[wid * 832 + 256]);
    unsigned* hist = histS[wid];

    // ---- load: lane holds x[8l .. 8l+7] ----
    const float4* xp4 = reinterpret_cast<const float4*>(x + (size_t)bc * 512);
    const float4 xa = xp4[2 * l], xb = xp4[2 * l + 1];
    float xe[8] = {xa.x, xa.y, xa.z, xa.w, xb.x, xb.y, xb.z, xb.w};

    // ---- pass 1: sums, min, max (+ 16-lane group sums for segment means) ----
    float psum = 0.f, s2 = 0.f, mn = xe[0], mx = xe[0];
#pragma unroll
    for (int e = 0; e < 8; e++) {
        psum += xe[e];
        s2 = fmaf(xe[e], xe[e], s2);
        mn = fminf(mn, xe[e]);
        mx = fmaxf(mx, xe[e]);
    }
    float g = psum;
#pragma unroll
    for (int m = 1; m < 16; m <<= 1) g += __shfl_xor(g, m, 64);
    const float g0 = __shfl(g, 0, 64), g1 = __shfl(g, 16, 64),
                g2 = __shfl(g, 32, 64), g3 = __shfl(g, 48, 64);
    const float S1 = (g0 + g1) + (g2 + g3);
#pragma unroll
    for (int m = 1; m < 64; m <<= 1) {
        s2 += __shfl_xor(s2, m, 64);
        mn = fminf(mn, __shfl_xor(mn, m, 64));
        mx = fmaxf(mx, __shfl_xor(mx, m, 64));
    }
    const float mean = S1 * (1.0f / 512.0f);

    // ---- pass 2: centered moments ----
    float c2 = 0.f, c3 = 0.f, c4 = 0.f;
#pragma unroll
    for (int e = 0; e < 8; e++) {
        float a = xe[e] - mean;
        float a2 = a * a;
        c2 += a2;
        c3 = fmaf(a2, a, c3);
        c4 = fmaf(a2, a2, c4);
    }
#pragma unroll
    for (int m = 1; m < 64; m <<= 1) {
        c2 += __shfl_xor(c2, m, 64);
        c3 += __shfl_xor(c3, m, 64);
        c4 += __shfl_xor(c4, m, 64);
    }
    const float m2 = c2 * (1.0f / 512.0f);
    const float m3 = c3 * (1.0f / 512.0f);
    const float m4 = c4 * (1.0f / 512.0f);
    const float stdv = sqrtf(m2);
    const float skew = m3 / (m2 * stdv);
    const float kurt = m4 / (m2 * m2) - 3.0f;
    const float rms = sqrtf(s2 * (1.0f / 512.0f));

    // ---- histogram (bit-exact fp32: sub, IEEE div, mul, trunc) ----
    if (l < 10) hist[l] = 0u;
    {
        float wdt = mx - mn;
        float safew = (wdt > 0.0f) ? wdt : 1.0f;
#pragma unroll
        for (int e = 0; e < 8; e++) {
            int bi = (int)((xe[e] - mn) / safew * 10.0f);
            bi = bi < 0 ? 0 : (bi > 9 ? 9 : bi);
            atomicAdd(&hist[bi], 1u);
        }
    }
    float entterm;
    {
        float cnt = (l < 10) ? (float)hist[l] : 0.0f;
        float p = cnt * (1.0f / 512.0f);
        entterm = (p > 0.0f) ? p * logf(p) : 0.0f;
#pragma unroll
        for (int m = 1; m < 16; m <<= 1) entterm += __shfl_xor(entterm, m, 64);
    }
    const float ent = -entterm;   // valid on lanes 0..15 (lane 6 uses it)

    // ---- hoisted twiddles (all from fp64-exact tables; W^m = (c, -s)) ----
    const int rb = l >> 4, n0 = l & 15;
    float2 tv;
    tv = tw16S[rb];             const float2 w16q1 = make_float2(tv.x, -tv.y);
    tv = tw16S[(2 * rb) & 15];  const float2 w16q2 = make_float2(tv.x, -tv.y);
    tv = tw16S[(3 * rb) & 15];  const float2 w16q3 = make_float2(tv.x, -tv.y);
    tv = twS[(4 * l) & 255];    const float2 step4 = make_float2(tv.x, -tv.y);
    tv = twS[l];                const float2 wq1 = make_float2(tv.x, -tv.y);
    tv = twS[(2 * l) & 255];    const float2 wq2 = make_float2(tv.x, -tv.y);
    tv = twS[(3 * l) & 255];    const float2 wq3 = make_float2(tv.x, -tv.y);
    // (-i)^((rb*a)&3) coefficients, a=0..3 (runtime rb -> +-1/0 floats)
    float car[4], cai[4];
#pragma unroll
    for (int a = 0; a < 4; a++) {
        int mm = (rb * a) & 3;
        car[a] = (mm == 0) ? 1.f : ((mm == 2) ? -1.f : 0.f);
        cai[a] = (mm == 1) ? -1.f : ((mm == 3) ? 1.f : 0.f);
    }

    // ---- Welch PSD: 3 segments, 256-pt DFT = (4x4) x (4x4) radix ----
    float P1 = 0.f, P2 = 0.f, P128 = 0.f;
#pragma unroll
    for (int s = 0; s < 3; s++) {
        const float smean =
            ((s == 0) ? (g0 + g1) : (s == 1) ? (g1 + g2) : (g2 + g3)) * (1.0f / 256.0f);
        const int D = l - 16 * s;   // active lanes hold 8 consecutive samples
        float alt = 0.f;
        if (D >= 0 && D < 32) {
            const float4 wA = reinterpret_cast<const float4*>(winS)[2 * D];
            const float4 wB = reinterpret_cast<const float4*>(winS)[2 * D + 1];
            float wv0 = wA.x * (xe[0] - smean);
            float wv1 = wA.y * (xe[1] - smean);
            float wv2 = wA.z * (xe[2] - smean);
            float wv3 = wA.w * (xe[3] - smean);
            float wv4 = wB.x * (xe[4] - smean);
            float wv5 = wB.y * (xe[5] - smean);
            float wv6 = wB.z * (xe[6] - smean);
            float wv7 = wB.w * (xe[7] - smean);
            reinterpret_cast<float4*>(vseg)[2 * D] = make_float4(wv0, wv1, wv2, wv3);
            reinterpret_cast<float4*>(vseg)[2 * D + 1] = make_float4(wv4, wv5, wv6, wv7);
            alt = ((wv0 - wv1) + (wv2 - wv3)) + ((wv4 - wv5) + (wv6 - wv7));
        }
        // X_128 = sum (-1)^n v_n  (real)
#pragma unroll
        for (int m = 1; m < 64; m <<= 1) alt += __shfl_xor(alt, m, 64);
        P128 = fmaf(alt, alt, P128);

        // stage 1: T[r][n0] = sum_n1 v[16 n1 + n0] W16^(r n1), r = rb + 4j
        float v[16];
#pragma unroll
        for (int n1 = 0; n1 < 16; n1++) v[n1] = vseg[16 * n1 + n0];
        float Dre[4], Dim[4];
#pragma unroll
        for (int q = 0; q < 4; q++) {
            float dr = v[q], di = 0.f;   // a=0 coeff = 1
#pragma unroll
            for (int a = 1; a < 4; a++) {
                float vv = v[4 * a + q];
                dr = fmaf(vv, car[a], dr);
                di = fmaf(vv, cai[a], di);
            }
            Dre[q] = dr; Dim[q] = di;
        }
        const float E0r = Dre[0], E0i = Dim[0];
        const float E1r = Dre[1] * w16q1.x - Dim[1] * w16q1.y;
        const float E1i = Dre[1] * w16q1.y + Dim[1] * w16q1.x;
        const float E2r = Dre[2] * w16q2.x - Dim[2] * w16q2.y;
        const float E2i = Dre[2] * w16q2.y + Dim[2] * w16q2.x;
        const float E3r = Dre[3] * w16q3.x - Dim[3] * w16q3.y;
        const float E3i = Dre[3] * w16q3.y + Dim[3] * w16q3.x;
        // T[rb+4j] = sum_q E_q * (-i)^(j q)   (compile-time sign/swap)
        T[(rb +  0) * 18 + n0] = make_float2((E0r + E1r) + (E2r + E3r),
                                             (E0i + E1i) + (E2i + E3i));
        T[(rb +  4) * 18 + n0] = make_float2((E0r + E1i) - (E2r + E3i),
                                             (E0i - E1r) + (E3r - E2i));
        T[(rb +  8) * 18 + n0] = make_float2((E0r - E1r) + (E2r - E3r),
                                             (E0i - E1i) + (E2i - E3i));
        T[(rb + 12) * 18 + n0] = make_float2((E0r - E1i) - (E2r - E3i),
                                             (E0i + E1r) - (E2i + E3r));

        // stage 2: k1 = l, k2 = l + 64 share row rr = l & 15
        float2 cur = make_float2(1.f, 0.f);
        float G0r = 0, G0i = 0, G1r = 0, G1i = 0, G2r = 0, G2i = 0, G3r = 0, G3i = 0;
#pragma unroll
        for (int a = 0; a < 4; a++) {
            const float4 t01 = *reinterpret_cast<const float4*>(&T[n0 * 18 + 4 * a]);
            const float4 t23 = *reinterpret_cast<const float4*>(&T[n0 * 18 + 4 * a + 2]);
            G0r = fmaf(t01.x, cur.x, fmaf(-t01.y, cur.y, G0r));
            G0i = fmaf(t01.x, cur.y, fmaf( t01.y, cur.x, G0i));
            G1r = fmaf(t01.z, cur.x, fmaf(-t01.w, cur.y, G1r));
            G1i = fmaf(t01.z, cur.y, fmaf( t01.w, cur.x, G1i));
            G2r = fmaf(t23.x, cur.x, fmaf(-t23.y, cur.y, G2r));
            G2i = fmaf(t23.x, cur.y, fmaf( t23.y, cur.x, G2i));
            G3r = fmaf(t23.z, cur.x, fmaf(-t23.w, cur.y, G3r));
            G3i = fmaf(t23.z, cur.y, fmaf( t23.w, cur.x, G3i));
            if (a < 3) {
                float nx = cur.x * step4.x - cur.y * step4.y;
                float ny = cur.x * step4.y + cur.y * step4.x;
                cur = make_float2(nx, ny);
            }
        }
        const float H0r = G0r, H0i = G0i;
        const float H1r = G1r * wq1.x - G1i * wq1.y, H1i = G1r * wq1.y + G1i * wq1.x;
        const float H2r = G2r * wq2.x - G2i * wq2.y, H2i = G2r * wq2.y + G2i * wq2.x;
        const float H3r = G3r * wq3.x - G3i * wq3.y, H3i = G3r * wq3.y + G3i * wq3.x;
        const float X1r = (H0r + H1r) + (H2r + H3r);
        const float X1i = (H0i + H1i) + (H2i + H3i);
        const float X2r = (H0r + H1i) - (H2r + H3i);   // sum H_q (-i)^q
        const float X2i = (H0i - H1r) + (H3r - H2i);
        P1 = fmaf(X1r, X1r, fmaf(X1i, X1i, P1));
        P2 = fmaf(X2r, X2r, fmaf(X2i, X2i, P2));
    }

    const float scc = (1.0f / 12288.0f) * (1.0f / 3.0f);
    const float psd1 = P1 * ((l == 0) ? 1.0f : 2.0f) * scc;   // k = l
    const float psd2 = P2 * 2.0f * scc;                        // k = l + 64
    const float psd128 = P128 * scc;                           // k = 128

    // ---- bands (trapz, dx = 0.5) + argmax ----
    auto wt = [](int k, int lo, int hi) -> float {
        if (k < lo || k > hi) return 0.0f;
        return (k == lo || k == hi) ? 0.25f : 0.5f;
    };
    float tot, al, be, de, ga, th, bv; int bi_;
    {
        const int k = l; const float p = psd1;
        tot = wt(k, 0, 128) * p;
        al = wt(k, 16, 24) * p; be = wt(k, 24, 60) * p; de = wt(k, 1, 8) * p;
        ga = wt(k, 60, 90) * p; th = wt(k, 8, 16) * p;
        bv = p; bi_ = k;
    }
    {
        const int k = l + 64; const float p = psd2;   // 64..127: interior of total
        tot += 0.5f * p;
        ga += wt(k, 60, 90) * p;
        if (p > bv) { bv = p; bi_ = k; }
    }
    if (l == 0) {
        tot += 0.25f * psd128;
        if (psd128 > bv) { bv = psd128; bi_ = 128; }
    }
#pragma unroll
    for (int m = 1; m < 64; m <<= 1) {
        tot += __shfl_xor(tot, m, 64);
        al  += __shfl_xor(al, m, 64);
        be  += __shfl_xor(be, m, 64);
        de  += __shfl_xor(de, m, 64);
        ga  += __shfl_xor(ga, m, 64);
        th  += __shfl_xor(th, m, 64);
        float ov = __shfl_xor(bv, m, 64);
        int   oi = __shfl_xor(bi_, m, 64);
        if (ov > bv || (ov == bv && oi < bi_)) { bv = ov; bi_ = oi; }
    }
    const bool ok = tot > 1e-6f;
    const float alR = ok ? al / tot : 0.f;
    const float beR = ok ? be / tot : 0.f;
    const float deR = ok ? de / tot : 0.f;
    const float gaR = ok ? ga / tot : 0.f;
    const float thR = ok ? th / tot : 0.f;
    const float pkf = 0.5f * (float)bi_;

    if (l < NF) {
        float fv =
            (l == 0)  ? al :
            (l == 1)  ? alR :
            (l == 2)  ? be :
            (l == 3)  ? beR :
            (l == 4)  ? de :
            (l == 5)  ? deR :
            (l == 6)  ? ent :
            (l == 7)  ? ga :
            (l == 8)  ? gaR :
            (l == 9)  ? kurt :
            (l == 10) ? mean :
            (l == 11) ? pkf :
            (l == 12) ? rms :
            (l == 13) ? skew :
            (l == 14) ? stdv :
            (l == 15) ? th : thR;
        out[(size_t)b * NCOL + POS[c] * NF + l] = fv;
    }
}

__global__ __launch_bounds__(256) void znorm_kernel(float* __restrict__ fm) {
    __shared__ float red[4];
    const int col = blockIdx.x;    // 1088 columns
    const int t = threadIdx.x;
    const int wid = t >> 6, lane = t & 63;
    float v[8];
    float s = 0.0f;
#pragma unroll
    for (int i = 0; i < 8; i++) {
        v[i] = fm[(size_t)(i * 256 + t) * NCOL + col];
        s += v[i];
    }
#pragma unroll
    for (int off = 32; off; off >>= 1) s += __shfl_down(s, off, 64);
    if (lane == 0) red[wid] = s;
    __syncthreads();
    const float mu = (red[0] + red[1] + red[2] + red[3]) * (1.0f / 2048.0f);
    __syncthreads();
    float q = 0.0f;
#pragma unroll
    for (int i = 0; i < 8; i++) {
        float dd = v[i] - mu;
        q += dd * dd;
    }
#pragma unroll
    for (int off = 32; off; off >>= 1) q += __shfl_down(q, off, 64);
    if (lane == 0) red[wid] = q;
    __syncthreads();
    const float sd = sqrtf((red[0] + red[1] + red[2] + red[3]) * (1.0f / 2048.0f));
    const float den = sd + 1e-6f;
#pragma unroll
    for (int i = 0; i < 8; i++)
        fm[(size_t)(i * 256 + t) * NCOL + col] = (v[i] - mu) / den;
}

extern "C" void kernel_launch(void* const* d_in, const int* in_sizes, int n_in,
                              void* d_out, int out_size, void* d_ws, size_t ws_size,
                              hipStream_t stream) {
    const float* x = (const float*)d_in[0];
    float* out = (float*)d_out;
    const int nblocks = (NB * NC) / 4;   // one wave per channel, 4 waves/block
    if (d_ws != nullptr && ws_size >= 4096) {
        float* win = (float*)d_ws;
        float2* tw = (float2*)((char*)d_ws + 1024);
        init_tables<<<1, 256, 0, stream>>>(win, tw);
        feat_kernel<true><<<nblocks, 256, 0, stream>>>(x, win, tw, out);
    } else {
        feat_kernel<false><<<nblocks, 256, 0, stream>>>(x, nullptr, nullptr, out);
    }
    znorm_kernel<<<NCOL, 256, 0, stream>>>(out);
}